// Round 14
// baseline (174.742 us; speedup 1.0000x reference)
//
#include <hip/hip_runtime.h>
#include <hip/hip_bf16.h>
#include <cstdint>
#include <cstddef>

typedef float  f32x4  __attribute__((ext_vector_type(4)));
typedef __bf16 bf16x8 __attribute__((ext_vector_type(8)));
typedef __bf16 bf16x4 __attribute__((ext_vector_type(4)));

#define HIDDEN 1024
#define SEQ    2048
#define BATCH  2
#define NQKV   3072
#define MTOT   4096

__device__ __forceinline__ __bf16 f2bf(float f) {
  unsigned u = __builtin_bit_cast(unsigned, f);
  u += 0x7FFFu + ((u >> 16) & 1u);          // round-to-nearest-even
  unsigned short s = (unsigned short)(u >> 16);
  return __builtin_bit_cast(__bf16, s);
}

// pack two f32 -> bf16x2 (round-half-up) in 3 VALU: 2 adds + 1 v_perm_b32
// (v_cvt_pk_bf16_f32 truncates on gfx950 — R9 correctness failure; keep pk2.)
__device__ __forceinline__ unsigned pk2(float a, float b) {
  unsigned ua = __builtin_bit_cast(unsigned, a) + 0x8000u;
  unsigned ub = __builtin_bit_cast(unsigned, b) + 0x8000u;
  return __builtin_amdgcn_perm(ub, ua, 0x07060302u);  // {hi16(ub), hi16(ua)}
}

__device__ __forceinline__ float fexp2(float x) {
#if __has_builtin(__builtin_amdgcn_exp2f)
  return __builtin_amdgcn_exp2f(x);   // bare v_exp_f32
#else
  return exp2f(x);
#endif
}

__device__ __forceinline__ void async16(const void* g, void* l) {
  __builtin_amdgcn_global_load_lds((__attribute__((address_space(1))) void*)(g),
                                   (__attribute__((address_space(3))) void*)(l),
                                   16, 0, 0);
}

#define MFMA16(a, b, c) __builtin_amdgcn_mfma_f32_16x16x32_bf16((a), (b), (c), 0, 0, 0)

// ---------------- prep: x->bf16 convert + both weight transposes (one launch) ----
__global__ __launch_bounds__(256) void k_prep(const float* __restrict__ x,
                                              __bf16* __restrict__ xb,
                                              const float* __restrict__ qkv_w,
                                              __bf16* __restrict__ wqkT,
                                              const float* __restrict__ out_w,
                                              __bf16* __restrict__ woT) {
  __shared__ float tile[64][65];
  const int bid = blockIdx.x, t = threadIdx.x;
  if (bid < 4096) {
    int i = bid * 256 + t;
    float4 v = ((const float4*)x)[i];
    bf16x4 o;
    o[0] = f2bf(v.x); o[1] = f2bf(v.y); o[2] = f2bf(v.z); o[3] = f2bf(v.w);
    ((bf16x4*)xb)[i] = o;
    return;
  }
  const float* W; __bf16* WT; int N, bx, by;
  if (bid < 4864) { int g = bid - 4096; W = qkv_w; WT = wqkT; N = NQKV;  bx = g % 48; by = g / 48; }
  else            { int g = bid - 4864; W = out_w; WT = woT;  N = HIDDEN; bx = g % 16; by = g / 16; }
  const int K = HIDDEN;
  int tx = t & 63, ty = t >> 6;
  int n0 = bx * 64, k0 = by * 64;
#pragma unroll
  for (int r = 0; r < 16; r++) {
    int row = r * 4 + ty;
    tile[row][tx] = W[(size_t)(k0 + row) * N + n0 + tx];
  }
  __syncthreads();
#pragma unroll
  for (int i2 = 0; i2 < 2; i2++) {
    int cc = i2 * 256 + t;
    int n = cc >> 3, ch = cc & 7;
    bf16x8 o;
#pragma unroll
    for (int j = 0; j < 8; j++) o[j] = f2bf(tile[ch * 8 + j][n]);
    *(bf16x8*)(WT + (size_t)(n0 + n) * K + k0 + ch * 8) = o;
  }
}

// ---------------- QKV GEMM: 256x192, BK=64, 4-phase counted schedule ------------
// R8 (verified): 8 waves (2M x 4N), per-wave 128x48, acc[8][3]; grid 256 = 1/CU,
// XCD-bijective 4bx x 8by. Phases (m-half x k-half), counted vmcnt(5)/tile,
// A halves bit-striped, B unsplit; chunk-XOR swizzle both sides.
__global__ __launch_bounds__(512, 2) void k_qkv(const __bf16* __restrict__ A,
                                                const __bf16* __restrict__ BT,
                                                const float* __restrict__ bias,
                                                __bf16* __restrict__ Cout,
                                                __bf16* __restrict__ vt) {
  const int K = HIDDEN;
  __shared__ __align__(16) __bf16 As[2][2][8192];   // [parity][half][128 striped rows x 64 k]
  __shared__ __align__(16) __bf16 Bs[2][12288];     // [parity][192 rows x 64 k]
  const int t = threadIdx.x;
  const int lane = t & 63, wv = t >> 6;
  const int ln = lane & 15, quad = lane >> 4;
  const int wm = (wv >> 2) * 128, wn = (wv & 3) * 48;

  const int lin = blockIdx.x;
  const int xcd = lin & 7, wi = lin >> 3;          // wi in [0,32)
  const int bxi = (xcd & 3) * 4 + (wi & 3);        // [0,16)
  const int byi = (xcd >> 2) * 8 + (wi >> 2);      // [0,16)
  const int m0 = byi * 256, n0 = bxi * 192;

  auto stA = [&](int kt, int h) {
    __bf16* dst = &As[kt & 1][h][0];
    const __bf16* src = A + (size_t)m0 * K + kt * 64;
#pragma unroll
    for (int i = 0; i < 2; i++) {
      int tt = i * 512 + t;
      int sr = tt >> 3, ch = tt & 7;
      int gr = (sr & 63) + ((sr >> 6) << 7) + h * 64;   // striped row
      async16(src + (size_t)gr * K + ((ch ^ (sr & 7)) * 8), dst + tt * 8);
    }
  };
  auto stB = [&](int kt) {
    __bf16* dst = &Bs[kt & 1][0];
    const __bf16* src = BT + (size_t)n0 * K + kt * 64;
#pragma unroll
    for (int i = 0; i < 3; i++) {
      int tt = i * 512 + t;
      int row = tt >> 3, ch = tt & 7;
      async16(src + (size_t)row * K + ((ch ^ (row & 7)) * 8), dst + tt * 8);
    }
  };

  const f32x4 zero4 = {0.f, 0.f, 0.f, 0.f};
  f32x4 acc[8][3];
#pragma unroll
  for (int i = 0; i < 8; i++)
#pragma unroll
    for (int j = 0; j < 3; j++) acc[i][j] = zero4;

  // prologue (FIFO: A(0,h0), B(0), A(0,h1), A(1,h0), B(1) = 12 loads)
  stA(0, 0); stB(0); stA(0, 1); stA(1, 0); stB(1);

  bf16x8 a0[4], a1[4], b0[3], b1[3];
  const int sra = ln + ((wv >> 2) << 6);        // in-half A row base (+ m*16)
  const int srb = (wv & 3) * 48 + ln;           // B row base (+ nt*16)
  const int swz = ln & 7;

  const int NT = K / 64;   // 16
  for (int kt = 0; kt < NT; kt++) {
    const int p = kt & 1;
    if (kt < NT - 1) asm volatile("s_waitcnt vmcnt(5)" ::: "memory");
    else             asm volatile("s_waitcnt vmcnt(0)" ::: "memory");
    __builtin_amdgcn_s_barrier();
    const __bf16* A0 = &As[p][0][0];
    const __bf16* A1 = &As[p][1][0];
    const __bf16* Bb = &Bs[p][0];
    // ---------------- P0: m-lo x k0-31
    {
#pragma unroll
      for (int m = 0; m < 4; m++)
        a0[m] = *(const bf16x8*)(A0 + (sra + m * 16) * 64 + ((quad ^ swz) * 8));
#pragma unroll
      for (int n = 0; n < 3; n++)
        b0[n] = *(const bf16x8*)(Bb + (srb + n * 16) * 64 + ((quad ^ swz) * 8));
      if (kt + 1 < NT) stA(kt + 1, 1);
      __builtin_amdgcn_s_barrier();
      asm volatile("s_waitcnt lgkmcnt(0)" ::: "memory");
      __builtin_amdgcn_sched_barrier(0);
      __builtin_amdgcn_s_setprio(1);
#pragma unroll
      for (int m = 0; m < 4; m++)
#pragma unroll
        for (int n = 0; n < 3; n++)
          acc[m][n] = MFMA16(a0[m], b0[n], acc[m][n]);
      __builtin_amdgcn_s_setprio(0);
      __builtin_amdgcn_s_barrier();
    }
    // ---------------- P1: m-lo x k32-63
    {
#pragma unroll
      for (int m = 0; m < 4; m++)
        a1[m] = *(const bf16x8*)(A0 + (sra + m * 16) * 64 + (((4 + quad) ^ swz) * 8));
#pragma unroll
      for (int n = 0; n < 3; n++)
        b1[n] = *(const bf16x8*)(Bb + (srb + n * 16) * 64 + (((4 + quad) ^ swz) * 8));
      __builtin_amdgcn_s_barrier();
      asm volatile("s_waitcnt lgkmcnt(0)" ::: "memory");
      __builtin_amdgcn_sched_barrier(0);
      __builtin_amdgcn_s_setprio(1);
#pragma unroll
      for (int m = 0; m < 4; m++)
#pragma unroll
        for (int n = 0; n < 3; n++)
          acc[m][n] = MFMA16(a1[m], b1[n], acc[m][n]);
      __builtin_amdgcn_s_setprio(0);
      __builtin_amdgcn_s_barrier();
    }
    // ---------------- P2: m-hi x k0-31 (b0 still live)
    {
#pragma unroll
      for (int m = 0; m < 4; m++)
        a0[m] = *(const bf16x8*)(A1 + (sra + m * 16) * 64 + ((quad ^ swz) * 8));
      if (kt + 2 < NT) stA(kt + 2, 0);
      __builtin_amdgcn_s_barrier();
      asm volatile("s_waitcnt lgkmcnt(0)" ::: "memory");
      __builtin_amdgcn_sched_barrier(0);
      __builtin_amdgcn_s_setprio(1);
#pragma unroll
      for (int m = 0; m < 4; m++)
#pragma unroll
        for (int n = 0; n < 3; n++)
          acc[4 + m][n] = MFMA16(a0[m], b0[n], acc[4 + m][n]);
      __builtin_amdgcn_s_setprio(0);
      __builtin_amdgcn_s_barrier();
    }
    // ---------------- P3: m-hi x k32-63 (b1 still live)
    {
#pragma unroll
      for (int m = 0; m < 4; m++)
        a1[m] = *(const bf16x8*)(A1 + (sra + m * 16) * 64 + (((4 + quad) ^ swz) * 8));
      if (kt + 2 < NT) stB(kt + 2);
      __builtin_amdgcn_s_barrier();
      asm volatile("s_waitcnt lgkmcnt(0)" ::: "memory");
      __builtin_amdgcn_sched_barrier(0);
      __builtin_amdgcn_s_setprio(1);
#pragma unroll
      for (int m = 0; m < 4; m++)
#pragma unroll
        for (int n = 0; n < 3; n++)
          acc[4 + m][n] = MFMA16(a1[m], b1[n], acc[4 + m][n]);
      __builtin_amdgcn_s_setprio(0);
      // closing barrier is the next kt's top {vmcnt; s_barrier}
    }
  }

  const float CE = 0.125f * 1.44269504089f;
#pragma unroll
  for (int nt = 0; nt < 3; nt++) {
    int g = n0 + wn + nt * 16;      // lane-uniform 16-col group base
    int col = g + ln;
    float bv = bias[col];
    int off = g % 192;
    if (off < 128) {
      float scl = (off < 64) ? CE : 1.0f;    // pre-scale Q by CE
#pragma unroll
      for (int mt = 0; mt < 8; mt++) {
#pragma unroll
        for (int r = 0; r < 4; r++) {
          int row = m0 + wm + mt * 16 + quad * 4 + r;
          Cout[(size_t)row * NQKV + col] = f2bf((acc[mt][nt][r] + bv) * scl);
        }
      }
    } else {
      // V path: vt[bh][d][sblk*128 + p], p = permuted in-block position
      int hg = g / 192;
      int d  = off - 128 + ln;
#pragma unroll
      for (int mt = 0; mt < 8; mt++) {
        int rowb = m0 + wm + mt * 16;        // + quad*4 + r
        int bb = rowb >> 11;
        int s  = rowb & 2047;
        int sblk = s >> 7;
        int blk  = (s >> 4) & 7;             // (s%128)/16
        int pp = (blk & 3) * 32 + quad * 8 + ((blk >> 2) << 2);
        uint2 o;
        o.x = pk2(acc[mt][nt][0] + bv, acc[mt][nt][1] + bv);
        o.y = pk2(acc[mt][nt][2] + bv, acc[mt][nt][3] + bv);
        *(uint2*)(vt + ((size_t)((bb * 16 + hg) * 64 + d)) * SEQ + sblk * 128 + pp) = o;
      }
    }
  }
}

// ---------------- out GEMM: 128x128, BK=64, 2-phase counted (R10-verified) ------
__global__ __launch_bounds__(512, 2) void k_out(const __bf16* __restrict__ A,
                                                const __bf16* __restrict__ BT,
                                                const float* __restrict__ bias,
                                                float* __restrict__ Cout) {
  const int K = HIDDEN, N = HIDDEN;
  __shared__ __align__(16) __bf16 As[2][2][4096];   // [parity][half][64 striped rows x 64 k]
  __shared__ __align__(16) __bf16 Bs[2][8192];      // [parity][128 rows x 64 k]
  const int t = threadIdx.x;
  const int lane = t & 63, wv = t >> 6;
  const int ln = lane & 15, quad = lane >> 4;
  const int wm = (wv >> 2) * 64, wn = (wv & 3) * 32;

  const int lin = blockIdx.x;
  const int xcd = lin & 7, wi = lin >> 3;          // wi in [0,32)
  const int bxi = (xcd & 1) * 4 + (wi & 3);        // [0,8)
  const int byi = (xcd >> 1) * 8 + (wi >> 2);      // [0,32)
  const int m0 = byi * 128, n0 = bxi * 128;

  auto stA = [&](int kt, int h) {                   // 1 load/thread
    __bf16* dst = &As[kt & 1][h][0];
    const __bf16* src = A + (size_t)m0 * K + kt * 64;
    int sr = t >> 3, ch = t & 7;
    int gr = (sr & 31) + ((sr >> 5) << 6) + h * 32;   // striped row
    async16(src + (size_t)gr * K + ((ch ^ (sr & 7)) * 8), dst + t * 8);
  };
  auto stB = [&](int kt) {                          // 2 loads/thread
    __bf16* dst = &Bs[kt & 1][0];
    const __bf16* src = BT + (size_t)n0 * K + kt * 64;
#pragma unroll
    for (int i = 0; i < 2; i++) {
      int tt = i * 512 + t;
      int row = tt >> 3, ch = tt & 7;
      async16(src + (size_t)row * K + ((ch ^ (row & 7)) * 8), dst + tt * 8);
    }
  };

  const f32x4 zero4 = {0.f, 0.f, 0.f, 0.f};
  f32x4 acc[4][2];
#pragma unroll
  for (int i = 0; i < 4; i++)
#pragma unroll
    for (int j = 0; j < 2; j++) acc[i][j] = zero4;

  // prologue (FIFO: A(0,h0), B(0), A(0,h1), A(1,h0), B(1) = 7 loads)
  stA(0, 0); stB(0); stA(0, 1); stA(1, 0); stB(1);

  bf16x8 af[2][2], bfr[2][2];
  const int sra = ln + ((wv >> 2) << 5);        // in-half A row base (+ m*16)
  const int srb = wn + ln;                      // B row base (+ n*16)
  const int swz = ln & 7;

  const int NT = K / 64;   // 16
  for (int kt = 0; kt < NT; kt++) {
    const int p = kt & 1;
    if (kt < NT - 1) asm volatile("s_waitcnt vmcnt(3)" ::: "memory");
    else             asm volatile("s_waitcnt vmcnt(0)" ::: "memory");
    __builtin_amdgcn_s_barrier();
    const __bf16* A0 = &As[p][0][0];
    const __bf16* A1 = &As[p][1][0];
    const __bf16* Bb = &Bs[p][0];
    // ---------------- P0: m-stripe0, full k; b loaded for both phases
    {
#pragma unroll
      for (int m = 0; m < 2; m++)
#pragma unroll
        for (int kk = 0; kk < 2; kk++)
          af[m][kk] = *(const bf16x8*)(A0 + (sra + m * 16) * 64 + (((kk * 4 + quad) ^ swz) * 8));
#pragma unroll
      for (int n = 0; n < 2; n++)
#pragma unroll
        for (int kk = 0; kk < 2; kk++)
          bfr[n][kk] = *(const bf16x8*)(Bb + (srb + n * 16) * 64 + (((kk * 4 + quad) ^ swz) * 8));
      if (kt + 1 < NT) stA(kt + 1, 1);
      __builtin_amdgcn_s_barrier();
      asm volatile("s_waitcnt lgkmcnt(0)" ::: "memory");
      __builtin_amdgcn_sched_barrier(0);
      __builtin_amdgcn_s_setprio(1);
#pragma unroll
      for (int m = 0; m < 2; m++)
#pragma unroll
        for (int n = 0; n < 2; n++) {
          acc[m][n] = MFMA16(af[m][0], bfr[n][0], acc[m][n]);
          acc[m][n] = MFMA16(af[m][1], bfr[n][1], acc[m][n]);
        }
      __builtin_amdgcn_s_setprio(0);
      __builtin_amdgcn_s_barrier();
    }
    // ---------------- P1: m-stripe1, full k (b reused)
    {
#pragma unroll
      for (int m = 0; m < 2; m++)
#pragma unroll
        for (int kk = 0; kk < 2; kk++)
          af[m][kk] = *(const bf16x8*)(A1 + (sra + m * 16) * 64 + (((kk * 4 + quad) ^ swz) * 8));
      if (kt + 2 < NT) { stA(kt + 2, 0); stB(kt + 2); }
      __builtin_amdgcn_s_barrier();
      asm volatile("s_waitcnt lgkmcnt(0)" ::: "memory");
      __builtin_amdgcn_sched_barrier(0);
      __builtin_amdgcn_s_setprio(1);
#pragma unroll
      for (int m = 0; m < 2; m++)
#pragma unroll
        for (int n = 0; n < 2; n++) {
          acc[2 + m][n] = MFMA16(af[m][0], bfr[n][0], acc[2 + m][n]);
          acc[2 + m][n] = MFMA16(af[m][1], bfr[n][1], acc[2 + m][n]);
        }
      __builtin_amdgcn_s_setprio(0);
      // closing barrier is the next kt's top {vmcnt; s_barrier}
    }
  }

  // epilogue: row = m0 + wm + h*32 + m*16 + quad*4 + r; col = n0 + wn + n*16 + ln
#pragma unroll
  for (int h = 0; h < 2; h++)
#pragma unroll
    for (int n = 0; n < 2; n++) {
      int col = n0 + wn + n * 16 + ln;
      float bv = bias[col];
#pragma unroll
      for (int m = 0; m < 2; m++)
#pragma unroll
        for (int r = 0; r < 4; r++) {
          int row = m0 + wm + h * 32 + m * 16 + quad * 4 + r;
          Cout[(size_t)row * N + col] = acc[h * 2 + m][n][r] + bv;
        }
    }
}

// ---------------- fused flash attention: static-max, register-P, MFMA row-sums ----
// R14: one-tile-deep software pipeline (T15): each body computes
// {QK^T(t+1) -> P_next} INTERLEAVED with {PV(t) using P_cur} — the two streams
// are independent, so the next tile's exp/pack VALU hides under this tile's PV
// MFMAs (previously fully serial per tile: QK^T -> exp -> PV).
//   - P double-buffered in NAMED register arrays Pa/Pb (no runtime indexing ->
//     no scratch, rule #20); loop hand-unrolled x2 so parity is compile-time.
//   - per-operand staging, full-drain __syncthreads (no counted-vmcnt):
//     body(t): barrier; issue K(t+2) [overwrites K(t), last read QK^T(t) in
//     body(t-1) — fenced]; issue V(t+1) [overwrites V(t-1), last read PV(t-1)
//     in body(t-1) — fenced]; compute QK^T(t+1) [K(t+1) drained by this
//     barrier] ∥ PV(t) [V(t) drained].
//   - prologue: stage K0,V0,K1; barrier; QK^T(0)->Pa. Tail: body(15) skips
//     QK^T(16)/stages. Barrier count unchanged (17 total).
//   - epilogue stage region = K par0: last read QK^T(14) in body(13), fenced by
//     body(14)+body(15) barriers; no writes to K par0 after body(12)'s issue
//     (K(14), drained body(13)) -> safe as before.
// R4: setprio around MFMA clusters; pk2 P-pack (cvt_pk truncates, R9).
__global__ __launch_bounds__(512, 4) void k_attn(const __bf16* __restrict__ qkv,
                                                 const __bf16* __restrict__ vt,
                                                 __bf16* __restrict__ aout) {
  __shared__ __align__(16) __bf16 smem[32768];   // 64 KB: K dbuf 2x16K, V dbuf 2x16K
  const int t = threadIdx.x;           // 0..511
  const int lane = t & 63, wv = t >> 6;
  const int ln = lane & 15, quad = lane >> 4;
  const int sw8 = (quad ^ ((ln >> 1) & 3)) * 8;

  int gid = blockIdx.x;
  int slot = gid & 7, j = gid >> 3;
  int bh = slot * 4 + (j >> 4);     // 4 (b,h) pairs per XCD slot -> K/V pinned in XCD L2
  int qt0 = j & 15;
  const int b = bh >> 4, h = bh & 15;
  const int q0 = qt0 * 128;

  const __bf16* qbase = qkv + (size_t)b * SEQ * NQKV + h * 192;
  const __bf16* kbase = qbase + 64;
  const __bf16* vbase = vt + (size_t)bh * 64 * SEQ;

  auto stageK = [&](int it) {
    __bf16* Kd = smem + (it & 1) * 8192;
    const __bf16* kn = kbase + (size_t)it * 128 * NQKV;
#pragma unroll
    for (int i = 0; i < 2; i++) {
      int tt = i * 512 + t;
      int hh = tt >> 9, row = (tt >> 2) & 127, ch = tt & 3;
      int chs = ch ^ ((row >> 1) & 3);
      async16(kn + (size_t)row * NQKV + hh * 32 + chs * 8, Kd + tt * 8);
    }
  };
  auto stageV = [&](int it) {
    __bf16* Vd = smem + 16384 + (it & 1) * 8192;
    const __bf16* vn = vbase + it * 128;
#pragma unroll
    for (int i = 0; i < 2; i++) {
      int tt = i * 512 + t;
      int c = tt >> 8, d = (tt >> 2) & 63, w = tt & 3;
      int ws = w ^ ((d >> 1) & 3);
      async16(vn + (size_t)d * SEQ + c * 32 + ws * 8, Vd + tt * 8);
    }
  };

  // prologue: K0, V0, K1 in flight
  stageK(0); stageV(0); stageK(1);

  // Q fragments (pre-scaled by CE): wave's 16 q rows, B-operand layout
  bf16x8 qf[2];
#pragma unroll
  for (int dc = 0; dc < 2; dc++)
    qf[dc] = *(const bf16x8*)(qbase + (size_t)(q0 + wv * 16 + ln) * NQKV + dc * 32 + quad * 8);

  union { unsigned u[4]; bf16x8 v; } ones;
  ones.u[0] = ones.u[1] = ones.u[2] = ones.u[3] = 0x3F803F80u;   // bf16 1.0 x8

  const f32x4 zero4 = {0.f, 0.f, 0.f, 0.f};
  f32x4 O[4];
  f32x4 Ol = zero4;                 // row-sums (l) via ones-MFMA, row-layout
#pragma unroll
  for (int dt = 0; dt < 4; dt++) O[dt] = zero4;

  unsigned Pa[8][2], Pb[8][2];

  auto qkt = [&](const __bf16* Ks, unsigned (&P)[8][2]) {
#pragma unroll
    for (int blk = 0; blk < 8; blk++) {
      bf16x8 kf0 = *(const bf16x8*)(Ks +        (blk * 16 + ln) * 32 + sw8);
      bf16x8 kf1 = *(const bf16x8*)(Ks + 4096 + (blk * 16 + ln) * 32 + sw8);
      __builtin_amdgcn_s_setprio(1);
      f32x4 s = MFMA16(kf0, qf[0], zero4);
      s = MFMA16(kf1, qf[1], s);
      __builtin_amdgcn_s_setprio(0);
      P[blk][0] = pk2(fexp2(s[0]), fexp2(s[1]));
      P[blk][1] = pk2(fexp2(s[2]), fexp2(s[3]));
    }
  };
  auto pv = [&](const __bf16* Vs, unsigned (&P)[8][2]) {
#pragma unroll
    for (int kc = 0; kc < 4; kc++) {
      union { bf16x8 v; unsigned u[4]; } pf;
      pf.u[0] = P[kc][0]; pf.u[1] = P[kc][1];
      pf.u[2] = P[kc + 4][0]; pf.u[3] = P[kc + 4][1];
      __builtin_amdgcn_s_setprio(1);
      Ol = MFMA16(pf.v, ones.v, Ol);
#pragma unroll
      for (int dt = 0; dt < 4; dt++) {
        bf16x8 vf = *(const bf16x8*)(Vs + kc * 2048 + (dt * 16 + ln) * 32 + sw8);
        O[dt] = MFMA16(pf.v, vf, O[dt]);
      }
      __builtin_amdgcn_s_setprio(0);
    }
  };

  __syncthreads();                  // K0, V0, K1 landed
  qkt(smem, Pa);                    // QK^T(0) from K par0

  for (int itp = 0; itp < 8; itp++) {
    const int itE = 2 * itp, itO = 2 * itp + 1;
    // ---- EVEN body: PV(itE, Pa) ∥ QK^T(itE+1 -> Pb)
    __syncthreads();                // drains K(itE+1), V(itE); fences prior reads
    if (itE + 2 < 16) stageK(itE + 2);   // par0, overwrites K(itE)
    stageV(itE + 1);                      // par1, overwrites V(itE-1); itE+1<=15 always
    qkt(smem + 8192, Pb);                 // K par1 = (itE+1)&1
    pv(smem + 16384, Pa);                 // V par0 = itE&1
    // ---- ODD body: PV(itO, Pb) ∥ QK^T(itO+1 -> Pa)
    __syncthreads();                // drains K(itO+1), V(itO); fences prior reads
    if (itO + 2 < 16) stageK(itO + 2);   // par1, overwrites K(itO)
    if (itO + 1 < 16) stageV(itO + 1);   // par0, overwrites V(itO-1)
    if (itO < 15) qkt(smem, Pa);          // K par0 = (itO+1)&1
    pv(smem + 16384 + 8192, Pb);          // V par1 = itO&1
  }

  // epilogue: Ol[r] = l for q-row quad*4+r (same row-layout as O) -> no shuffles.
  // stage region = K par0: last read QK^T(14) in body(13); fenced by the
  // body(14)/body(15) barriers all waves passed; no later writes to K par0.
  __bf16* stage = smem + wv * 1024;   // wave-private 16x64
#pragma unroll
  for (int r = 0; r < 4; r++) {
    float ir = 1.0f / Ol[r];
#pragma unroll
    for (int dt = 0; dt < 4; dt++)
      stage[(quad * 4 + r) * 64 + dt * 16 + ln] = f2bf(O[dt][r] * ir);
  }
  __bf16* obase = aout + (size_t)(b * SEQ + q0 + wv * 16) * HIDDEN + h * 64;
#pragma unroll
  for (int i = 0; i < 2; i++) {
    int tt = i * 64 + lane; int row = tt >> 3, ch = tt & 7;
    *(bf16x8*)(obase + (size_t)row * HIDDEN + ch * 8) = *(const bf16x8*)(stage + row * 64 + ch * 8);
  }
}

extern "C" void kernel_launch(void* const* d_in, const int* in_sizes, int n_in,
                              void* d_out, int out_size, void* d_ws, size_t ws_size,
                              hipStream_t stream) {
  const float* x     = (const float*)d_in[0];
  const float* qkv_w = (const float*)d_in[1];
  const float* qkv_b = (const float*)d_in[2];
  const float* out_w = (const float*)d_in[3];
  const float* out_b = (const float*)d_in[4];

  char* ws = (char*)d_ws;
  __bf16* xb   = (__bf16*)(ws);                       // 4096*1024*2   =  8,388,608
  __bf16* wqkT = (__bf16*)(ws + 8388608);             // 3072*1024*2   =  6,291,456
  __bf16* woT  = (__bf16*)(ws + 14680064);            // 1024*1024*2   =  2,097,152
  __bf16* qkv  = (__bf16*)(ws + 16777216);            // 4096*3072*2   = 25,165,824 (V cols unused)
  __bf16* vt   = (__bf16*)(ws + 41943040);            // 32*64*2048*2  =  8,388,608
  __bf16* aout = (__bf16*)(ws + 50331648);            // 4096*1024*2   =  8,388,608

  k_prep<<<5120, 256, 0, stream>>>(x, xb, qkv_w, wqkT, out_w, woT);
  k_qkv<<<256, 512, 0, stream>>>(xb, wqkT, qkv_b, qkv, vt);
  k_attn<<<512, 512, 0, stream>>>(qkv, vt, aout);
  k_out<<<256, 512, 0, stream>>>(aout, woT, out_b, (float*)d_out);
}

// Round 15
// 172.169 us; speedup vs baseline: 1.0149x; 1.0149x over previous
//
#include <hip/hip_runtime.h>
#include <hip/hip_bf16.h>
#include <cstdint>
#include <cstddef>

typedef float  f32x4  __attribute__((ext_vector_type(4)));
typedef __bf16 bf16x8 __attribute__((ext_vector_type(8)));
typedef __bf16 bf16x4 __attribute__((ext_vector_type(4)));

#define HIDDEN 1024
#define SEQ    2048
#define BATCH  2
#define NQKV   3072
#define MTOT   4096

__device__ __forceinline__ __bf16 f2bf(float f) {
  unsigned u = __builtin_bit_cast(unsigned, f);
  u += 0x7FFFu + ((u >> 16) & 1u);          // round-to-nearest-even
  unsigned short s = (unsigned short)(u >> 16);
  return __builtin_bit_cast(__bf16, s);
}

// pack two f32 -> bf16x2 (round-half-up) in 3 VALU: 2 adds + 1 v_perm_b32
// (v_cvt_pk_bf16_f32 truncates on gfx950 — R9 correctness failure; keep pk2.)
__device__ __forceinline__ unsigned pk2(float a, float b) {
  unsigned ua = __builtin_bit_cast(unsigned, a) + 0x8000u;
  unsigned ub = __builtin_bit_cast(unsigned, b) + 0x8000u;
  return __builtin_amdgcn_perm(ub, ua, 0x07060302u);  // {hi16(ub), hi16(ua)}
}

__device__ __forceinline__ float fexp2(float x) {
#if __has_builtin(__builtin_amdgcn_exp2f)
  return __builtin_amdgcn_exp2f(x);   // bare v_exp_f32
#else
  return exp2f(x);
#endif
}

__device__ __forceinline__ void async16(const void* g, void* l) {
  __builtin_amdgcn_global_load_lds((__attribute__((address_space(1))) void*)(g),
                                   (__attribute__((address_space(3))) void*)(l),
                                   16, 0, 0);
}

#define MFMA16(a, b, c) __builtin_amdgcn_mfma_f32_16x16x32_bf16((a), (b), (c), 0, 0, 0)

// ---------------- prep: x->bf16 convert + both weight transposes (one launch) ----
__global__ __launch_bounds__(256) void k_prep(const float* __restrict__ x,
                                              __bf16* __restrict__ xb,
                                              const float* __restrict__ qkv_w,
                                              __bf16* __restrict__ wqkT,
                                              const float* __restrict__ out_w,
                                              __bf16* __restrict__ woT) {
  __shared__ float tile[64][65];
  const int bid = blockIdx.x, t = threadIdx.x;
  if (bid < 4096) {
    int i = bid * 256 + t;
    float4 v = ((const float4*)x)[i];
    bf16x4 o;
    o[0] = f2bf(v.x); o[1] = f2bf(v.y); o[2] = f2bf(v.z); o[3] = f2bf(v.w);
    ((bf16x4*)xb)[i] = o;
    return;
  }
  const float* W; __bf16* WT; int N, bx, by;
  if (bid < 4864) { int g = bid - 4096; W = qkv_w; WT = wqkT; N = NQKV;  bx = g % 48; by = g / 48; }
  else            { int g = bid - 4864; W = out_w; WT = woT;  N = HIDDEN; bx = g % 16; by = g / 16; }
  const int K = HIDDEN;
  int tx = t & 63, ty = t >> 6;
  int n0 = bx * 64, k0 = by * 64;
#pragma unroll
  for (int r = 0; r < 16; r++) {
    int row = r * 4 + ty;
    tile[row][tx] = W[(size_t)(k0 + row) * N + n0 + tx];
  }
  __syncthreads();
#pragma unroll
  for (int i2 = 0; i2 < 2; i2++) {
    int cc = i2 * 256 + t;
    int n = cc >> 3, ch = cc & 7;
    bf16x8 o;
#pragma unroll
    for (int j = 0; j < 8; j++) o[j] = f2bf(tile[ch * 8 + j][n]);
    *(bf16x8*)(WT + (size_t)(n0 + n) * K + k0 + ch * 8) = o;
  }
}

// ---------------- QKV GEMM: 256x192, BK=64, 4-phase counted schedule ------------
// R8 (verified): 8 waves (2M x 4N), per-wave 128x48, acc[8][3]; grid 256 = 1/CU,
// XCD-bijective 4bx x 8by. Phases (m-half x k-half), counted vmcnt(5)/tile,
// A halves bit-striped, B unsplit; chunk-XOR swizzle both sides.
__global__ __launch_bounds__(512, 2) void k_qkv(const __bf16* __restrict__ A,
                                                const __bf16* __restrict__ BT,
                                                const float* __restrict__ bias,
                                                __bf16* __restrict__ Cout,
                                                __bf16* __restrict__ vt) {
  const int K = HIDDEN;
  __shared__ __align__(16) __bf16 As[2][2][8192];   // [parity][half][128 striped rows x 64 k]
  __shared__ __align__(16) __bf16 Bs[2][12288];     // [parity][192 rows x 64 k]
  const int t = threadIdx.x;
  const int lane = t & 63, wv = t >> 6;
  const int ln = lane & 15, quad = lane >> 4;
  const int wm = (wv >> 2) * 128, wn = (wv & 3) * 48;

  const int lin = blockIdx.x;
  const int xcd = lin & 7, wi = lin >> 3;          // wi in [0,32)
  const int bxi = (xcd & 3) * 4 + (wi & 3);        // [0,16)
  const int byi = (xcd >> 2) * 8 + (wi >> 2);      // [0,16)
  const int m0 = byi * 256, n0 = bxi * 192;

  auto stA = [&](int kt, int h) {
    __bf16* dst = &As[kt & 1][h][0];
    const __bf16* src = A + (size_t)m0 * K + kt * 64;
#pragma unroll
    for (int i = 0; i < 2; i++) {
      int tt = i * 512 + t;
      int sr = tt >> 3, ch = tt & 7;
      int gr = (sr & 63) + ((sr >> 6) << 7) + h * 64;   // striped row
      async16(src + (size_t)gr * K + ((ch ^ (sr & 7)) * 8), dst + tt * 8);
    }
  };
  auto stB = [&](int kt) {
    __bf16* dst = &Bs[kt & 1][0];
    const __bf16* src = BT + (size_t)n0 * K + kt * 64;
#pragma unroll
    for (int i = 0; i < 3; i++) {
      int tt = i * 512 + t;
      int row = tt >> 3, ch = tt & 7;
      async16(src + (size_t)row * K + ((ch ^ (row & 7)) * 8), dst + tt * 8);
    }
  };

  const f32x4 zero4 = {0.f, 0.f, 0.f, 0.f};
  f32x4 acc[8][3];
#pragma unroll
  for (int i = 0; i < 8; i++)
#pragma unroll
    for (int j = 0; j < 3; j++) acc[i][j] = zero4;

  // prologue (FIFO: A(0,h0), B(0), A(0,h1), A(1,h0), B(1) = 12 loads)
  stA(0, 0); stB(0); stA(0, 1); stA(1, 0); stB(1);

  bf16x8 a0[4], a1[4], b0[3], b1[3];
  const int sra = ln + ((wv >> 2) << 6);        // in-half A row base (+ m*16)
  const int srb = (wv & 3) * 48 + ln;           // B row base (+ nt*16)
  const int swz = ln & 7;

  const int NT = K / 64;   // 16
  for (int kt = 0; kt < NT; kt++) {
    const int p = kt & 1;
    if (kt < NT - 1) asm volatile("s_waitcnt vmcnt(5)" ::: "memory");
    else             asm volatile("s_waitcnt vmcnt(0)" ::: "memory");
    __builtin_amdgcn_s_barrier();
    const __bf16* A0 = &As[p][0][0];
    const __bf16* A1 = &As[p][1][0];
    const __bf16* Bb = &Bs[p][0];
    // ---------------- P0: m-lo x k0-31
    {
#pragma unroll
      for (int m = 0; m < 4; m++)
        a0[m] = *(const bf16x8*)(A0 + (sra + m * 16) * 64 + ((quad ^ swz) * 8));
#pragma unroll
      for (int n = 0; n < 3; n++)
        b0[n] = *(const bf16x8*)(Bb + (srb + n * 16) * 64 + ((quad ^ swz) * 8));
      if (kt + 1 < NT) stA(kt + 1, 1);
      __builtin_amdgcn_s_barrier();
      asm volatile("s_waitcnt lgkmcnt(0)" ::: "memory");
      __builtin_amdgcn_sched_barrier(0);
      __builtin_amdgcn_s_setprio(1);
#pragma unroll
      for (int m = 0; m < 4; m++)
#pragma unroll
        for (int n = 0; n < 3; n++)
          acc[m][n] = MFMA16(a0[m], b0[n], acc[m][n]);
      __builtin_amdgcn_s_setprio(0);
      __builtin_amdgcn_s_barrier();
    }
    // ---------------- P1: m-lo x k32-63
    {
#pragma unroll
      for (int m = 0; m < 4; m++)
        a1[m] = *(const bf16x8*)(A0 + (sra + m * 16) * 64 + (((4 + quad) ^ swz) * 8));
#pragma unroll
      for (int n = 0; n < 3; n++)
        b1[n] = *(const bf16x8*)(Bb + (srb + n * 16) * 64 + (((4 + quad) ^ swz) * 8));
      __builtin_amdgcn_s_barrier();
      asm volatile("s_waitcnt lgkmcnt(0)" ::: "memory");
      __builtin_amdgcn_sched_barrier(0);
      __builtin_amdgcn_s_setprio(1);
#pragma unroll
      for (int m = 0; m < 4; m++)
#pragma unroll
        for (int n = 0; n < 3; n++)
          acc[m][n] = MFMA16(a1[m], b1[n], acc[m][n]);
      __builtin_amdgcn_s_setprio(0);
      __builtin_amdgcn_s_barrier();
    }
    // ---------------- P2: m-hi x k0-31 (b0 still live)
    {
#pragma unroll
      for (int m = 0; m < 4; m++)
        a0[m] = *(const bf16x8*)(A1 + (sra + m * 16) * 64 + ((quad ^ swz) * 8));
      if (kt + 2 < NT) stA(kt + 2, 0);
      __builtin_amdgcn_s_barrier();
      asm volatile("s_waitcnt lgkmcnt(0)" ::: "memory");
      __builtin_amdgcn_sched_barrier(0);
      __builtin_amdgcn_s_setprio(1);
#pragma unroll
      for (int m = 0; m < 4; m++)
#pragma unroll
        for (int n = 0; n < 3; n++)
          acc[4 + m][n] = MFMA16(a0[m], b0[n], acc[4 + m][n]);
      __builtin_amdgcn_s_setprio(0);
      __builtin_amdgcn_s_barrier();
    }
    // ---------------- P3: m-hi x k32-63 (b1 still live)
    {
#pragma unroll
      for (int m = 0; m < 4; m++)
        a1[m] = *(const bf16x8*)(A1 + (sra + m * 16) * 64 + (((4 + quad) ^ swz) * 8));
      if (kt + 2 < NT) stB(kt + 2);
      __builtin_amdgcn_s_barrier();
      asm volatile("s_waitcnt lgkmcnt(0)" ::: "memory");
      __builtin_amdgcn_sched_barrier(0);
      __builtin_amdgcn_s_setprio(1);
#pragma unroll
      for (int m = 0; m < 4; m++)
#pragma unroll
        for (int n = 0; n < 3; n++)
          acc[4 + m][n] = MFMA16(a1[m], b1[n], acc[4 + m][n]);
      __builtin_amdgcn_s_setprio(0);
      // closing barrier is the next kt's top {vmcnt; s_barrier}
    }
  }

  const float CE = 0.125f * 1.44269504089f;
#pragma unroll
  for (int nt = 0; nt < 3; nt++) {
    int g = n0 + wn + nt * 16;      // lane-uniform 16-col group base
    int col = g + ln;
    float bv = bias[col];
    int off = g % 192;
    if (off < 128) {
      float scl = (off < 64) ? CE : 1.0f;    // pre-scale Q by CE
#pragma unroll
      for (int mt = 0; mt < 8; mt++) {
#pragma unroll
        for (int r = 0; r < 4; r++) {
          int row = m0 + wm + mt * 16 + quad * 4 + r;
          Cout[(size_t)row * NQKV + col] = f2bf((acc[mt][nt][r] + bv) * scl);
        }
      }
    } else {
      // V path: vt[bh][d][sblk*128 + p], p = permuted in-block position
      int hg = g / 192;
      int d  = off - 128 + ln;
#pragma unroll
      for (int mt = 0; mt < 8; mt++) {
        int rowb = m0 + wm + mt * 16;        // + quad*4 + r
        int bb = rowb >> 11;
        int s  = rowb & 2047;
        int sblk = s >> 7;
        int blk  = (s >> 4) & 7;             // (s%128)/16
        int pp = (blk & 3) * 32 + quad * 8 + ((blk >> 2) << 2);
        uint2 o;
        o.x = pk2(acc[mt][nt][0] + bv, acc[mt][nt][1] + bv);
        o.y = pk2(acc[mt][nt][2] + bv, acc[mt][nt][3] + bv);
        *(uint2*)(vt + ((size_t)((bb * 16 + hg) * 64 + d)) * SEQ + sblk * 128 + pp) = o;
      }
    }
  }
}

// ---------------- out GEMM: 128x128, BK=64, 2-phase counted (R10-verified) ------
__global__ __launch_bounds__(512, 2) void k_out(const __bf16* __restrict__ A,
                                                const __bf16* __restrict__ BT,
                                                const float* __restrict__ bias,
                                                float* __restrict__ Cout) {
  const int K = HIDDEN, N = HIDDEN;
  __shared__ __align__(16) __bf16 As[2][2][4096];   // [parity][half][64 striped rows x 64 k]
  __shared__ __align__(16) __bf16 Bs[2][8192];      // [parity][128 rows x 64 k]
  const int t = threadIdx.x;
  const int lane = t & 63, wv = t >> 6;
  const int ln = lane & 15, quad = lane >> 4;
  const int wm = (wv >> 2) * 64, wn = (wv & 3) * 32;

  const int lin = blockIdx.x;
  const int xcd = lin & 7, wi = lin >> 3;          // wi in [0,32)
  const int bxi = (xcd & 1) * 4 + (wi & 3);        // [0,8)
  const int byi = (xcd >> 1) * 8 + (wi >> 2);      // [0,32)
  const int m0 = byi * 128, n0 = bxi * 128;

  auto stA = [&](int kt, int h) {                   // 1 load/thread
    __bf16* dst = &As[kt & 1][h][0];
    const __bf16* src = A + (size_t)m0 * K + kt * 64;
    int sr = t >> 3, ch = t & 7;
    int gr = (sr & 31) + ((sr >> 5) << 6) + h * 32;   // striped row
    async16(src + (size_t)gr * K + ((ch ^ (sr & 7)) * 8), dst + t * 8);
  };
  auto stB = [&](int kt) {                          // 2 loads/thread
    __bf16* dst = &Bs[kt & 1][0];
    const __bf16* src = BT + (size_t)n0 * K + kt * 64;
#pragma unroll
    for (int i = 0; i < 2; i++) {
      int tt = i * 512 + t;
      int row = tt >> 3, ch = tt & 7;
      async16(src + (size_t)row * K + ((ch ^ (row & 7)) * 8), dst + tt * 8);
    }
  };

  const f32x4 zero4 = {0.f, 0.f, 0.f, 0.f};
  f32x4 acc[4][2];
#pragma unroll
  for (int i = 0; i < 4; i++)
#pragma unroll
    for (int j = 0; j < 2; j++) acc[i][j] = zero4;

  // prologue (FIFO: A(0,h0), B(0), A(0,h1), A(1,h0), B(1) = 7 loads)
  stA(0, 0); stB(0); stA(0, 1); stA(1, 0); stB(1);

  bf16x8 af[2][2], bfr[2][2];
  const int sra = ln + ((wv >> 2) << 5);        // in-half A row base (+ m*16)
  const int srb = wn + ln;                      // B row base (+ n*16)
  const int swz = ln & 7;

  const int NT = K / 64;   // 16
  for (int kt = 0; kt < NT; kt++) {
    const int p = kt & 1;
    if (kt < NT - 1) asm volatile("s_waitcnt vmcnt(3)" ::: "memory");
    else             asm volatile("s_waitcnt vmcnt(0)" ::: "memory");
    __builtin_amdgcn_s_barrier();
    const __bf16* A0 = &As[p][0][0];
    const __bf16* A1 = &As[p][1][0];
    const __bf16* Bb = &Bs[p][0];
    // ---------------- P0: m-stripe0, full k; b loaded for both phases
    {
#pragma unroll
      for (int m = 0; m < 2; m++)
#pragma unroll
        for (int kk = 0; kk < 2; kk++)
          af[m][kk] = *(const bf16x8*)(A0 + (sra + m * 16) * 64 + (((kk * 4 + quad) ^ swz) * 8));
#pragma unroll
      for (int n = 0; n < 2; n++)
#pragma unroll
        for (int kk = 0; kk < 2; kk++)
          bfr[n][kk] = *(const bf16x8*)(Bb + (srb + n * 16) * 64 + (((kk * 4 + quad) ^ swz) * 8));
      if (kt + 1 < NT) stA(kt + 1, 1);
      __builtin_amdgcn_s_barrier();
      asm volatile("s_waitcnt lgkmcnt(0)" ::: "memory");
      __builtin_amdgcn_sched_barrier(0);
      __builtin_amdgcn_s_setprio(1);
#pragma unroll
      for (int m = 0; m < 2; m++)
#pragma unroll
        for (int n = 0; n < 2; n++) {
          acc[m][n] = MFMA16(af[m][0], bfr[n][0], acc[m][n]);
          acc[m][n] = MFMA16(af[m][1], bfr[n][1], acc[m][n]);
        }
      __builtin_amdgcn_s_setprio(0);
      __builtin_amdgcn_s_barrier();
    }
    // ---------------- P1: m-stripe1, full k (b reused)
    {
#pragma unroll
      for (int m = 0; m < 2; m++)
#pragma unroll
        for (int kk = 0; kk < 2; kk++)
          af[m][kk] = *(const bf16x8*)(A1 + (sra + m * 16) * 64 + (((kk * 4 + quad) ^ swz) * 8));
      if (kt + 2 < NT) { stA(kt + 2, 0); stB(kt + 2); }
      __builtin_amdgcn_s_barrier();
      asm volatile("s_waitcnt lgkmcnt(0)" ::: "memory");
      __builtin_amdgcn_sched_barrier(0);
      __builtin_amdgcn_s_setprio(1);
#pragma unroll
      for (int m = 0; m < 2; m++)
#pragma unroll
        for (int n = 0; n < 2; n++) {
          acc[2 + m][n] = MFMA16(af[m][0], bfr[n][0], acc[2 + m][n]);
          acc[2 + m][n] = MFMA16(af[m][1], bfr[n][1], acc[2 + m][n]);
        }
      __builtin_amdgcn_s_setprio(0);
      // closing barrier is the next kt's top {vmcnt; s_barrier}
    }
  }

  // epilogue: row = m0 + wm + h*32 + m*16 + quad*4 + r; col = n0 + wn + n*16 + ln
#pragma unroll
  for (int h = 0; h < 2; h++)
#pragma unroll
    for (int n = 0; n < 2; n++) {
      int col = n0 + wn + n * 16 + ln;
      float bv = bias[col];
#pragma unroll
      for (int m = 0; m < 2; m++)
#pragma unroll
        for (int r = 0; r < 4; r++) {
          int row = m0 + wm + h * 32 + m * 16 + quad * 4 + r;
          Cout[(size_t)row * N + col] = acc[h * 2 + m][n][r] + bv;
        }
    }
}

// ---------------- fused flash attention: static-max, register-P, MFMA row-sums ----
// R15 = revert to the verified-best R10/R13 k_attn (pre-committed after R14's
// T15 pipeline regressed 42.9 -> 47.0 us, matching m253: T15 doesn't transfer
// to plain MFMA/VALU interleave — the 4-waves/SIMD TLP already hides exp/pack).
// R4: s_setprio(1) around MFMA clusters (T5) — verified 45.5 -> 43.5 us.
// pk2 (round-half-up) P-pack — cvt_pk truncates on gfx950 (R9 fail).
__global__ __launch_bounds__(512, 4) void k_attn(const __bf16* __restrict__ qkv,
                                                 const __bf16* __restrict__ vt,
                                                 __bf16* __restrict__ aout) {
  __shared__ __align__(16) __bf16 smem[32768];   // 64 KB: K dbuf 2x16K, V dbuf 2x16K
  const int t = threadIdx.x;           // 0..511
  const int lane = t & 63, wv = t >> 6;
  const int ln = lane & 15, quad = lane >> 4;
  const int sw8 = (quad ^ ((ln >> 1) & 3)) * 8;

  int gid = blockIdx.x;
  int slot = gid & 7, j = gid >> 3;
  int bh = slot * 4 + (j >> 4);     // 4 (b,h) pairs per XCD slot -> K/V pinned in XCD L2
  int qt0 = j & 15;
  const int b = bh >> 4, h = bh & 15;
  const int q0 = qt0 * 128;

  const __bf16* qbase = qkv + (size_t)b * SEQ * NQKV + h * 192;
  const __bf16* kbase = qbase + 64;
  const __bf16* vbase = vt + (size_t)bh * 64 * SEQ;

  // prologue: stage K(0), V(0) into parity-0 buffers (source-chunk swizzled)
#pragma unroll
  for (int i = 0; i < 2; i++) {
    int tt = i * 512 + t;
    int hh = tt >> 9, row = (tt >> 2) & 127, ch = tt & 3;
    int chs = ch ^ ((row >> 1) & 3);
    async16(kbase + (size_t)row * NQKV + hh * 32 + chs * 8, smem + tt * 8);
  }
#pragma unroll
  for (int i = 0; i < 2; i++) {
    int tt = i * 512 + t;
    int c = tt >> 8, d = (tt >> 2) & 63, w = tt & 3;
    int ws = w ^ ((d >> 1) & 3);
    async16(vbase + (size_t)d * SEQ + c * 32 + ws * 8, smem + 16384 + tt * 8);
  }

  // Q fragments (pre-scaled by CE): wave's 16 q rows, B-operand layout
  bf16x8 qf[2];
#pragma unroll
  for (int dc = 0; dc < 2; dc++)
    qf[dc] = *(const bf16x8*)(qbase + (size_t)(q0 + wv * 16 + ln) * NQKV + dc * 32 + quad * 8);

  union { unsigned u[4]; bf16x8 v; } ones;
  ones.u[0] = ones.u[1] = ones.u[2] = ones.u[3] = 0x3F803F80u;   // bf16 1.0 x8

  const f32x4 zero4 = {0.f, 0.f, 0.f, 0.f};
  f32x4 O[4];
  f32x4 Ol = zero4;                 // row-sums (l) via ones-MFMA, row-layout
#pragma unroll
  for (int dt = 0; dt < 4; dt++) O[dt] = zero4;

  for (int it = 0; it < SEQ / 128; it++) {
    __syncthreads();   // K(it)/V(it) landed; (it-1)'s buffers fully consumed
    const __bf16* Ks = smem + (it & 1) * 8192;
    const __bf16* Vs = smem + 16384 + (it & 1) * 8192;
    if (it + 1 < SEQ / 128) {   // prefetch next tile; flies over this tile's compute
      __bf16* Kd = smem + ((it + 1) & 1) * 8192;
      __bf16* Vd = smem + 16384 + ((it + 1) & 1) * 8192;
      const __bf16* kn = kbase + (size_t)(it + 1) * 128 * NQKV;
      const __bf16* vn = vbase + (it + 1) * 128;
#pragma unroll
      for (int i = 0; i < 2; i++) {
        int tt = i * 512 + t;
        int hh = tt >> 9, row = (tt >> 2) & 127, ch = tt & 3;
        int chs = ch ^ ((row >> 1) & 3);
        async16(kn + (size_t)row * NQKV + hh * 32 + chs * 8, Kd + tt * 8);
      }
#pragma unroll
      for (int i = 0; i < 2; i++) {
        int tt = i * 512 + t;
        int c = tt >> 8, d = (tt >> 2) & 63, w = tt & 3;
        int ws = w ^ ((d >> 1) & 3);
        async16(vn + (size_t)d * SEQ + c * 32 + ws * 8, Vd + tt * 8);
      }
    }

    // S^T = K * Q^T per 16-row blk; P = exp2(S^T) packed to bf16 immediately
    unsigned Pp[8][2];
#pragma unroll
    for (int blk = 0; blk < 8; blk++) {
      bf16x8 kf0 = *(const bf16x8*)(Ks +        (blk * 16 + ln) * 32 + sw8);
      bf16x8 kf1 = *(const bf16x8*)(Ks + 4096 + (blk * 16 + ln) * 32 + sw8);
      __builtin_amdgcn_s_setprio(1);
      f32x4 s = MFMA16(kf0, qf[0], zero4);
      s = MFMA16(kf1, qf[1], s);
      __builtin_amdgcn_s_setprio(0);
      Pp[blk][0] = pk2(fexp2(s[0]), fexp2(s[1]));
      Pp[blk][1] = pk2(fexp2(s[2]), fexp2(s[3]));
    }
    // O += P*V; Ol += P*1 (row-sums) — all on the MFMA pipe
#pragma unroll
    for (int kc = 0; kc < 4; kc++) {
      union { bf16x8 v; unsigned u[4]; } pf;
      pf.u[0] = Pp[kc][0]; pf.u[1] = Pp[kc][1];
      pf.u[2] = Pp[kc + 4][0]; pf.u[3] = Pp[kc + 4][1];
      __builtin_amdgcn_s_setprio(1);
      Ol = MFMA16(pf.v, ones.v, Ol);
#pragma unroll
      for (int dt = 0; dt < 4; dt++) {
        bf16x8 vf = *(const bf16x8*)(Vs + kc * 2048 + (dt * 16 + ln) * 32 + sw8);
        O[dt] = MFMA16(pf.v, vf, O[dt]);
      }
      __builtin_amdgcn_s_setprio(0);
    }
  }

  // epilogue: Ol[r] = l for q-row quad*4+r (same row-layout as O) -> no shuffles.
  __bf16* stage = smem + wv * 1024;   // wave-private 16x64
#pragma unroll
  for (int r = 0; r < 4; r++) {
    float ir = 1.0f / Ol[r];
#pragma unroll
    for (int dt = 0; dt < 4; dt++)
      stage[(quad * 4 + r) * 64 + dt * 16 + ln] = f2bf(O[dt][r] * ir);
  }
  __bf16* obase = aout + (size_t)(b * SEQ + q0 + wv * 16) * HIDDEN + h * 64;
#pragma unroll
  for (int i = 0; i < 2; i++) {
    int tt = i * 64 + lane; int row = tt >> 3, ch = tt & 7;
    *(bf16x8*)(obase + (size_t)row * HIDDEN + ch * 8) = *(const bf16x8*)(stage + row * 64 + ch * 8);
  }
}

extern "C" void kernel_launch(void* const* d_in, const int* in_sizes, int n_in,
                              void* d_out, int out_size, void* d_ws, size_t ws_size,
                              hipStream_t stream) {
  const float* x     = (const float*)d_in[0];
  const float* qkv_w = (const float*)d_in[1];
  const float* qkv_b = (const float*)d_in[2];
  const float* out_w = (const float*)d_in[3];
  const float* out_b = (const float*)d_in[4];

  char* ws = (char*)d_ws;
  __bf16* xb   = (__bf16*)(ws);                       // 4096*1024*2   =  8,388,608
  __bf16* wqkT = (__bf16*)(ws + 8388608);             // 3072*1024*2   =  6,291,456
  __bf16* woT  = (__bf16*)(ws + 14680064);            // 1024*1024*2   =  2,097,152
  __bf16* qkv  = (__bf16*)(ws + 16777216);            // 4096*3072*2   = 25,165,824 (V cols unused)
  __bf16* vt   = (__bf16*)(ws + 41943040);            // 32*64*2048*2  =  8,388,608
  __bf16* aout = (__bf16*)(ws + 50331648);            // 4096*1024*2   =  8,388,608

  k_prep<<<5120, 256, 0, stream>>>(x, xb, qkv_w, wqkT, out_w, woT);
  k_qkv<<<256, 512, 0, stream>>>(xb, wqkT, qkv_b, qkv, vt);
  k_attn<<<512, 512, 0, stream>>>(qkv, vt, aout);
  k_out<<<256, 512, 0, stream>>>(aout, woT, out_b, (float*)d_out);
}